// Round 1
// baseline (9083.675 us; speedup 1.0000x reference)
//
#include <hip/hip_runtime.h>
#include <math.h>

#define NV 4096
#define NN (NV*NV)
#define BM 128
#define BK 32
#define NKT (NV/BK)
#define THREADS 256

typedef __bf16 bf16_t;
typedef __bf16 bf16x8 __attribute__((ext_vector_type(8)));
typedef float f32x4 __attribute__((ext_vector_type(4)));

struct Flush {
  int nprev;
  int do_flush;
  int k_is_2;
  const bf16_t* prev[7];
  float cprev[7][4];
  float cself[4];
};

// ---------------------------------------------------------------------------
// Init: T1 = L - I (bf16), out_f = C0h_f * I + C1_f * T1  (fp32, all 4 planes)
// ---------------------------------------------------------------------------
__global__ void init_kernel(const float* __restrict__ L, bf16_t* __restrict__ T1,
                            float* __restrict__ out,
                            float c00, float c01, float c02, float c03,
                            float c10, float c11, float c12, float c13) {
  for (int idx = blockIdx.x * blockDim.x + threadIdx.x; idx < NN;
       idx += gridDim.x * blockDim.x) {
    int row = idx >> 12, col = idx & (NV - 1);
    float d = (row == col) ? 1.0f : 0.0f;
    float t1 = L[idx] - d;
    T1[idx] = (bf16_t)t1;
    out[(size_t)0 * NN + idx] = c10 * t1 + c00 * d;
    out[(size_t)1 * NN + idx] = c11 * t1 + c01 * d;
    out[(size_t)2 * NN + idx] = c12 * t1 + c02 * d;
    out[(size_t)3 * NN + idx] = c13 * t1 + c03 * d;
  }
}

// ---------------------------------------------------------------------------
// One Chebyshev step: Tnew = 2 * (T1 @ Bcur) - Told   (all symmetric, bf16)
// Optional flush: out_f += sum_j cprev[j][f]*prev[j] + cself[f]*Tnew
// ---------------------------------------------------------------------------
__global__ __launch_bounds__(THREADS) void cheb_step(
    const bf16_t* __restrict__ Amat,   // T1 (A operand; x2 applied in epilogue)
    const bf16_t* __restrict__ Bcur,   // T_{k-1}
    const bf16_t* __restrict__ Told,   // T_{k-2} (null if k==2 -> identity)
    bf16_t* __restrict__ Tnew,
    float* __restrict__ out,
    Flush fi) {
  __shared__ bf16_t sA[2][BM][BK];
  __shared__ bf16_t sB[2][BM][BK];

  const int t = threadIdx.x;
  const int l = t & 63;
  const int w = t >> 6;
  const int m0 = blockIdx.x * BM;
  const int n0 = blockIdx.y * BM;
  const int wr = (w >> 1) * 64;
  const int wc = (w & 1) * 64;
  const int lr = l >> 4;     // k-group (0..3)
  const int lc = l & 15;

  // staging: both operands are row-panels (symmetry => B == B^T)
  auto stage = [&](int buf, int kt) {
    const bf16_t* ga = Amat + (size_t)m0 * NV + kt * BK;
    const bf16_t* gb = Bcur + (size_t)n0 * NV + kt * BK;
#pragma unroll
    for (int r = 0; r < 2; ++r) {
      int off = r * 256 + t;          // 16B-unit index, wave-contiguous
      int row = off >> 2, c8 = off & 3;
      __builtin_amdgcn_global_load_lds(
          (const __attribute__((address_space(1))) unsigned int*)(ga + (size_t)row * NV + c8 * 8),
          (__attribute__((address_space(3))) unsigned int*)(&sA[buf][row][c8 * 8]),
          16, 0, 0);
      __builtin_amdgcn_global_load_lds(
          (const __attribute__((address_space(1))) unsigned int*)(gb + (size_t)row * NV + c8 * 8),
          (__attribute__((address_space(3))) unsigned int*)(&sB[buf][row][c8 * 8]),
          16, 0, 0);
    }
  };

  f32x4 acc[4][4] = {};

  stage(0, 0);
  __syncthreads();

  for (int kt = 0; kt < NKT; ++kt) {
    int cur = kt & 1;
    if (kt + 1 < NKT) stage(cur ^ 1, kt + 1);
    bf16x8 a[4], b[4];
#pragma unroll
    for (int m = 0; m < 4; ++m)
      a[m] = *(const bf16x8*)&sA[cur][wr + m * 16 + lc][lr * 8];
#pragma unroll
    for (int n = 0; n < 4; ++n)
      b[n] = *(const bf16x8*)&sB[cur][wc + n * 16 + lc][lr * 8];
#pragma unroll
    for (int m = 0; m < 4; ++m)
#pragma unroll
      for (int n = 0; n < 4; ++n)
        acc[m][n] = __builtin_amdgcn_mfma_f32_16x16x32_bf16(a[m], b[n], acc[m][n], 0, 0, 0);
    __syncthreads();
  }

  // epilogue: C/D layout col = lane&15, row = (lane>>4)*4 + reg  [verified m89/m91]
  const int rbase = m0 + wr + lr * 4;
  const int cbase = n0 + wc + lc;
#pragma unroll
  for (int m = 0; m < 4; ++m) {
#pragma unroll
    for (int n = 0; n < 4; ++n) {
#pragma unroll
      for (int r = 0; r < 4; ++r) {
        int row = rbase + m * 16 + r;
        int col = cbase + n * 16;
        size_t idx = (size_t)row * NV + col;
        float v = 2.0f * acc[m][n][r];
        if (fi.k_is_2) v -= (row == col) ? 1.0f : 0.0f;
        else           v -= (float)Told[idx];
        bf16_t vb = (bf16_t)v;
        Tnew[idx] = vb;
        if (fi.do_flush) {
          float tv = (float)vb;
          float s[4];
#pragma unroll
          for (int f = 0; f < 4; ++f) s[f] = fi.cself[f] * tv;
          for (int j = 0; j < fi.nprev; ++j) {
            float tj = (float)fi.prev[j][idx];
#pragma unroll
            for (int f = 0; f < 4; ++f) s[f] += fi.cprev[j][f] * tj;
          }
#pragma unroll
          for (int f = 0; f < 4; ++f) out[(size_t)f * NN + idx] += s[f];
        }
      }
    }
  }
}

// ---------------------------------------------------------------------------
extern "C" void kernel_launch(void* const* d_in, const int* in_sizes, int n_in,
                              void* d_out, int out_size, void* d_ws, size_t ws_size,
                              hipStream_t stream) {
  const float* L = (const float*)d_in[0];
  float* out = (float*)d_out;

  // Chebyshev coefficients (host, double precision), pre-scaled by sqrt(N)=64
  const double taus[4] = {0.5, 1.0, 2.0, 4.0};
  float C[33][4];
  for (int o = 0; o < 33; ++o)
    for (int f = 0; f < 4; ++f) {
      double s = 0.0;
      for (int j = 0; j < 33; ++j) {
        double th = M_PI * (j + 0.5) / 33.0;
        s += cos(o * th) * exp(-taus[f] * (cos(th) + 1.0));
      }
      C[o][f] = (float)((2.0 / 33.0) * s * 64.0);
    }

  // workspace layout: [T1][ring0][ring1]...
  const size_t bufB = (size_t)NN * sizeof(bf16_t);   // 32 MiB
  char* ws = (char*)d_ws;
  bf16_t* T1 = (bf16_t*)ws;
  int navail = (int)(ws_size / bufB) - 1;            // ring buffers available
  int G, ring;
  if (navail >= 8)      { G = 8; ring = 8; }
  else if (navail >= 4) { G = 4; ring = 4; }
  else                  { G = 2; ring = 3; }
  bf16_t* ringb[8];
  for (int i = 0; i < ring; ++i) ringb[i] = (bf16_t*)(ws + bufB * (size_t)(1 + i));

  hipLaunchKernelGGL(init_kernel, dim3(2048), dim3(256), 0, stream, L, T1, out,
                     0.5f * C[0][0], 0.5f * C[0][1], 0.5f * C[0][2], 0.5f * C[0][3],
                     C[1][0], C[1][1], C[1][2], C[1][3]);

  Flush fi;
  int pend = 0;
  int pend_slot[8];
  float pend_c[8][4];
  const bf16_t* Bprev = T1;
  const bf16_t* Told = nullptr;
  dim3 grid(NV / BM, NV / BM), blk(THREADS);

  for (int k = 2; k <= 32; ++k) {
    int slot = (k - 2) % ring;
    bf16_t* Tnew = ringb[slot];
    bool flush = (pend + 1 == G) || (k == 32);
    fi.nprev = 0;
    fi.do_flush = flush ? 1 : 0;
    fi.k_is_2 = (k == 2) ? 1 : 0;
    for (int f = 0; f < 4; ++f) fi.cself[f] = C[k][f];
    if (flush) {
      fi.nprev = pend;
      for (int j = 0; j < pend; ++j) {
        fi.prev[j] = ringb[pend_slot[j]];
        for (int f = 0; f < 4; ++f) fi.cprev[j][f] = pend_c[j][f];
      }
    }
    hipLaunchKernelGGL(cheb_step, grid, blk, 0, stream,
                       (const bf16_t*)T1, Bprev, Told, Tnew, out, fi);
    if (flush) {
      pend = 0;
    } else {
      pend_slot[pend] = slot;
      for (int f = 0; f < 4; ++f) pend_c[pend][f] = C[k][f];
      ++pend;
    }
    Told = Bprev;
    Bprev = Tnew;
  }
}